// Round 8
// baseline (4361.662 us; speedup 1.0000x reference)
//
#include <hip/hip_runtime.h>

// RNN: B=64, T=512, I=1024, H=1024, fp32 in/out.
// Phase 0: transpose-convert Wx/Wh -> bf16 [N][K] in ws.
// Phase 1: xproj = x @ Wx + bx + bh (bf16 MFMA, fp32 accum) -> d_out.
// Phase 2: persistent MFMA scan, 64 blocks x 512 thr = 8 clusters x 8 members.
//   cluster c: batches c*8..+8; member m: cols m*128..+128; wave w: k-slice
//   w*128 AND batch c*8+w's finisher/publisher/stager.
//   DECENTRALIZED per-wave protocol (2 barriers/step, no handoff):
//     wave: publish 64 h-dwords (sc0sc1) -> vmcnt(0) [publish-only queue] ->
//     lane0 per-wave flag -> all waves poll the cluster's 64 flags (1 line)
//     -> stage own batch row -> #D. MALL-based, placement-agnostic,
//     replay-safe (nothing cached: all sync traffic is sc0 sc1).

#define Bdim 64
#define Tdim 512
#define Idim 1024
#define Hdim 1024
#define Mdim (Bdim * Tdim)  // 32768

typedef __attribute__((ext_vector_type(8))) short bf16x8;
typedef __attribute__((ext_vector_type(4))) float f32x4;
typedef __attribute__((ext_vector_type(4))) unsigned int u32x4;

__device__ __forceinline__ float tanh_fast(float x) {
  float e = __expf(2.0f * x);
  return 1.0f - 2.0f / (e + 1.0f);
}
__device__ __forceinline__ unsigned int f2bf(float f) {
  unsigned int u = __float_as_uint(f);
  return (u + 0x7FFFu + ((u >> 16) & 1u)) >> 16;  // RNE
}
__device__ __forceinline__ unsigned int pack2(float lo, float hi) {
  return f2bf(lo) | (f2bf(hi) << 16);
}

// ---------------- Phase 0: fp32 [K][N] -> bf16 transposed [N][K] -------------
__global__ __launch_bounds__(256) void cvt_transpose(
    const float* __restrict__ src, unsigned short* __restrict__ dst) {
  __shared__ float t[32][33];
  const int bx = blockIdx.x * 32;
  const int by = blockIdx.y * 32;
  const int ty = threadIdx.x >> 3;
  const int tx = threadIdx.x & 7;
  float4 v = *(const float4*)&src[(size_t)(by + ty) * 1024 + bx + tx * 4];
  t[ty][tx * 4 + 0] = v.x; t[ty][tx * 4 + 1] = v.y;
  t[ty][tx * 4 + 2] = v.z; t[ty][tx * 4 + 3] = v.w;
  __syncthreads();
  ushort4 o;
  o.x = (unsigned short)f2bf(t[tx * 4 + 0][ty]);
  o.y = (unsigned short)f2bf(t[tx * 4 + 1][ty]);
  o.z = (unsigned short)f2bf(t[tx * 4 + 2][ty]);
  o.w = (unsigned short)f2bf(t[tx * 4 + 3][ty]);
  *(ushort4*)&dst[(size_t)(bx + ty) * 1024 + by + tx * 4] = o;
}

// ---------------- Phase 1: bf16 MFMA GEMM, 128x128 tile, BK=32 ---------------
__global__ __launch_bounds__(256) void xg_mfma(
    const float* __restrict__ X,            // [M][K] fp32
    const unsigned short* __restrict__ WxT, // [N][K] bf16
    const float* __restrict__ bx, const float* __restrict__ bh,
    float* __restrict__ C) {                // [M][N] fp32
  __shared__ char sAB[16384] __attribute__((aligned(16)));
  char* sA = sAB;
  char* sB = sAB + 8192;
  const int tid = threadIdx.x;
  const int m0 = blockIdx.y * 128;
  const int n0 = blockIdx.x * 128;
  const int w = tid >> 6, l = tid & 63;
  const int wm = (w >> 1) * 64, wn = (w & 1) * 64;
  const int r2 = tid >> 1, kh = tid & 1;

  f32x4 acc[4][4];
#pragma unroll
  for (int i = 0; i < 4; ++i)
#pragma unroll
    for (int j = 0; j < 4; ++j) acc[i][j] = (f32x4){0.f, 0.f, 0.f, 0.f};

  for (int k0 = 0; k0 < Idim; k0 += 32) {
    const float* xa = &X[(size_t)(m0 + r2) * Idim + k0 + kh * 16];
    float4 a0 = *(const float4*)(xa + 0), a1 = *(const float4*)(xa + 4);
    float4 a2 = *(const float4*)(xa + 8), a3 = *(const float4*)(xa + 12);
    const char* wb = (const char*)&WxT[(size_t)(n0 + r2) * Idim + k0 + kh * 16];
    u32x4 b0 = *(const u32x4*)wb;
    u32x4 b1 = *(const u32x4*)(wb + 16);
    __syncthreads();
    u32x4 pa0 = {pack2(a0.x, a0.y), pack2(a0.z, a0.w),
                 pack2(a1.x, a1.y), pack2(a1.z, a1.w)};
    u32x4 pa1 = {pack2(a2.x, a2.y), pack2(a2.z, a2.w),
                 pack2(a3.x, a3.y), pack2(a3.z, a3.w)};
    const int sw = (r2 & 7) << 4;
    const int rb = r2 * 64 + kh * 32;
    *(u32x4*)(sA + ((rb + 0) ^ sw)) = pa0;
    *(u32x4*)(sA + ((rb + 16) ^ sw)) = pa1;
    *(u32x4*)(sB + ((rb + 0) ^ sw)) = b0;
    *(u32x4*)(sB + ((rb + 16) ^ sw)) = b1;
    __syncthreads();
    bf16x8 af[4], bf[4];
#pragma unroll
    for (int i = 0; i < 4; ++i) {
      int ra = wm + i * 16 + (l & 15);
      af[i] = *(const bf16x8*)(sA + ((ra * 64 + (l >> 4) * 16) ^ ((ra & 7) << 4)));
      int rn = wn + i * 16 + (l & 15);
      bf[i] = *(const bf16x8*)(sB + ((rn * 64 + (l >> 4) * 16) ^ ((rn & 7) << 4)));
    }
#pragma unroll
    for (int i = 0; i < 4; ++i)
#pragma unroll
      for (int j = 0; j < 4; ++j)
        acc[i][j] = __builtin_amdgcn_mfma_f32_16x16x32_bf16(af[i], bf[j],
                                                            acc[i][j], 0, 0, 0);
  }
  float bias[4];
#pragma unroll
  for (int j = 0; j < 4; ++j) {
    int cc = n0 + wn + j * 16 + (l & 15);
    bias[j] = bx[cc] + bh[cc];
  }
#pragma unroll
  for (int i = 0; i < 4; ++i) {
    int rbase = m0 + wm + i * 16 + (l >> 4) * 4;
#pragma unroll
    for (int j = 0; j < 4; ++j) {
      int cc = n0 + wn + j * 16 + (l & 15);
#pragma unroll
      for (int r = 0; r < 4; ++r)
        C[(size_t)(rbase + r) * Hdim + cc] = acc[i][j][r] + bias[j];
    }
  }
}

// ---------------- flag clear (sc1 stores -> MALL) ----------------------------
__global__ void clear_flags(unsigned int* flags) {
  __hip_atomic_store(&flags[threadIdx.x], 0u, __ATOMIC_RELAXED,
                     __HIP_MEMORY_SCOPE_AGENT);
}

// ---------------- Phase 2: persistent MFMA scan ------------------------------
__global__ __launch_bounds__(512, 2) void rnn_scan(
    const unsigned short* __restrict__ WhT,  // [N=1024][K=1024] bf16
    float* __restrict__ out,                 // [B][T][H]: xproj in, h out
    float* __restrict__ hlast,               // [B][H]
    unsigned int* hbuf,                      // ws: [2][64 b][512 cp] dwords
    unsigned int* flags) {                   // ws: [8 cl][8 m][8 w]
  const int bid = blockIdx.x;
  const int c = bid & 7;   // cluster: batches c*8..+8 (XCD-local likely)
  const int m = bid >> 3;  // member: cols m*128..+128
  const int tid = threadIdx.x;
  const int w = tid >> 6;  // wave: k-slice w*128..+128; finisher batch c*8+w
  const int l = tid & 63;
  const int n0 = m * 128;

  __shared__ char smem[16384 + 33792] __attribute__((aligned(16)));
  char* smh = smem;          // h: [8 b][2048 B] bf16, XOR-swizzled
  char* smp = smem + 16384;  // partials: [8 w][8 nt][33][16 B] (lanes 0-31)

  // B-frags: Wh[k=w*128..+128][cols n0..+128] -> 8 nt x 4 kt = 128 VGPR/lane
  bf16x8 bfrag[32];
  {
    const int kb = (w << 7) + ((l >> 4) << 3);
    const int col = n0 + (l & 15);
#pragma unroll
    for (int nt = 0; nt < 8; ++nt)
#pragma unroll
      for (int kt = 0; kt < 4; ++kt)
        bfrag[nt * 4 + kt] =
            *(const bf16x8*)&WhT[(size_t)(col + nt * 16) * 1024 + kb + kt * 32];
  }

  // finisher: (batch fb = w, col pair c0 = 2*l)
  const int cpl = l;
  const int c0 = cpl * 2;
  const int b_abs = c * 8 + w;
  const int nt0 = c0 >> 4;
  const int lane0 = ((w >> 2) << 4) | (c0 & 15);  // 0..31
  const int regb = (w & 3) * 4;
  const size_t obase = (size_t)b_abs * ((size_t)Tdim * Hdim) + n0 + c0;
  unsigned int* pub = &hbuf[(size_t)b_abs * 512 + m * 64 + cpl];
  unsigned int* myflag = &flags[c * 64 + m * 8 + w];
  const unsigned int* pollf = &flags[c * 64 + l];

  float2 xp = *(const float2*)&out[obase];  // xproj t=0

  for (int t = 0; t < Tdim; ++t) {
    float sum0 = 0.f, sum1 = 0.f;
    if (t > 0) {
      // A-frags from swizzled LDS (rows = 8 batches, dup to 16)
      const int arow = l & 7;
      const int abase = arow * 2048 + (w << 8) + ((l >> 4) << 4);
      const int sw = arow << 4;
      bf16x8 af[4];
#pragma unroll
      for (int kt = 0; kt < 4; ++kt)
        af[kt] = *(const bf16x8*)(smh + ((abase + kt * 64) ^ sw));
#pragma unroll
      for (int nt = 0; nt < 8; ++nt) {
        f32x4 a = {0.f, 0.f, 0.f, 0.f};
#pragma unroll
        for (int kt = 0; kt < 4; ++kt)
          a = __builtin_amdgcn_mfma_f32_16x16x32_bf16(af[kt], bfrag[nt * 4 + kt],
                                                      a, 0, 0, 0);
        if (l < 32)  // lanes 32-63 hold duplicate rows 8-15: discard
          *(f32x4*)(smp + (((w * 8 + nt) * 33 + l) << 4)) = a;
      }
      asm volatile("s_waitcnt lgkmcnt(0)" ::: "memory");
      __builtin_amdgcn_s_barrier();  // #A: partials visible
      asm volatile("" ::: "memory");
#pragma unroll
      for (int w8 = 0; w8 < 8; ++w8) {
        const char* p = smp + (((w8 * 8 + nt0) * 33 + lane0) << 4) + regb;
        sum0 += *(const float*)p;
        sum1 += *(const float*)(p + 16);
      }
    }
    float h0 = tanh_fast(xp.x + sum0);
    float h1 = tanh_fast(xp.y + sum1);
    if (t == Tdim - 1) {
      *(float2*)&out[obase + (size_t)t * Hdim] = make_float2(h0, h1);
      *(float2*)&hlast[(size_t)b_abs * Hdim + n0 + c0] = make_float2(h0, h1);
      break;
    }
    const int par = (t + 1) & 1;
    // ---- per-wave publish -> ack -> flag (VMEM queue is empty here) ----
    __hip_atomic_store(pub + par * 32768, pack2(h0, h1), __ATOMIC_RELAXED,
                       __HIP_MEMORY_SCOPE_AGENT);
    asm volatile("s_waitcnt vmcnt(0)" ::: "memory");  // publish acked at MALL
    if (l == 0)
      __hip_atomic_store(myflag, (unsigned int)(t + 1), __ATOMIC_RELAXED,
                         __HIP_MEMORY_SCOPE_AGENT);
    // ---- every wave polls the cluster's 64 per-wave flags (one line) ----
    {
      const unsigned int tgt = (unsigned int)(t + 1);
      for (;;) {
        unsigned int v;
        asm volatile(
            "global_load_dword %0, %1, off sc0 sc1\n\ts_waitcnt vmcnt(0)"
            : "=v"(v) : "v"(pollf) : "memory");
        if (__ballot(v >= tgt) == ~0ull) break;
      }
    }
    // off-critical-path HBM ops + staging, one shared drain
    *(float2*)&out[obase + (size_t)t * Hdim] = make_float2(h0, h1);
    xp = *(const float2*)&out[obase + (size_t)(t + 1) * Hdim];
    {
      const char* src = (const char*)hbuf + (size_t)par * 131072 +
                        (size_t)(c * 8 + w) * 2048 + l * 32;
      u32x4 d0, d1;
      asm volatile(
          "global_load_dwordx4 %0, %2, off sc0 sc1\n\t"
          "global_load_dwordx4 %1, %2, off offset:16 sc0 sc1\n\t"
          "s_waitcnt vmcnt(0)"
          : "=&v"(d0), "=&v"(d1) : "v"(src) : "memory");
      __builtin_amdgcn_sched_barrier(0);
      const int base = w * 2048 + l * 32;
      const int sw = w << 4;
      *(u32x4*)(smh + (base ^ sw)) = d0;
      *(u32x4*)(smh + ((base + 16) ^ sw)) = d1;
    }
    asm volatile("s_waitcnt lgkmcnt(0)" ::: "memory");
    __builtin_amdgcn_s_barrier();  // #D: h_{t+1} staged
    asm volatile("" ::: "memory");
  }
}

extern "C" void kernel_launch(void* const* d_in, const int* in_sizes, int n_in,
                              void* d_out, int out_size, void* d_ws,
                              size_t ws_size, hipStream_t stream) {
  const float* x  = (const float*)d_in[0];
  const float* Wx = (const float*)d_in[1];
  const float* bx = (const float*)d_in[2];
  const float* Wh = (const float*)d_in[3];
  const float* bh = (const float*)d_in[4];
  float* out = (float*)d_out;
  float* hlast = out + (size_t)Bdim * Tdim * Hdim;
  unsigned int* flags = (unsigned int*)d_ws;                       // 2 KB
  unsigned int* hbuf = (unsigned int*)((char*)d_ws + 4096);        // 256 KB
  unsigned short* WxT = (unsigned short*)((char*)d_ws + 4096 + 262144);
  unsigned short* WhT = (unsigned short*)((char*)d_ws + 4096 + 262144 + 2097152);

  clear_flags<<<1, dim3(512), 0, stream>>>(flags);
  dim3 gt(32, 32);
  cvt_transpose<<<gt, dim3(256), 0, stream>>>(Wx, WxT);
  cvt_transpose<<<gt, dim3(256), 0, stream>>>(Wh, WhT);
  xg_mfma<<<dim3(Hdim / 128, Mdim / 128), dim3(256), 0, stream>>>(x, WxT, bx,
                                                                  bh, out);
  rnn_scan<<<dim3(64), dim3(512), 0, stream>>>(WhT, out, hlast, hbuf, flags);
}

// Round 9
// 1525.785 us; speedup vs baseline: 2.8586x; 2.8586x over previous
//
#include <hip/hip_runtime.h>

// RNN: B=64, T=512, I=1024, H=1024, fp32 in/out.
// Phase 0: transpose-convert Wx/Wh -> bf16 [N][K] in ws.
// Phase 1: xproj = x @ Wx + bx + bh (bf16 MFMA, fp32 accum) -> d_out.
// Phase 2: persistent MFMA scan, 64 blocks x 512 thr = 8 clusters x 8 members.
//   cluster c = {bid: bid&7==c} (one XCD under round-robin dispatch).
//   TWO-TIER SYNC:
//   - FAST (XCD-local, engaged only after runtime verification): sc0-only
//     (L1-bypass, L2-coherent) publish/flag/poll/stage through the XCD's L2.
//     Per-wave flags, all-wave hot poll (safe on local L2), 2 barriers/step.
//   - FALLBACK (R7-proven, MALL sc0sc1): publish -> vmcnt(2) -> barrier ->
//     block flag -> wave7 poll w/ s_sleep(2) -> barrier -> stage.
//   Detection: XCC_ID equality across cluster (via MALL) AND an sc0
//   ping-pong witness with timeout -- tests exactly the visibility property
//   the fast path requires; unanimous vote or everyone falls back.
//   Replay-safe: kernel-boundary release flushes dirty L2; tags/flags
//   cleared by clear kernel each launch; tags monotone within launch.

#define Bdim 64
#define Tdim 512
#define Idim 1024
#define Hdim 1024
#define Mdim (Bdim * Tdim)  // 32768

typedef __attribute__((ext_vector_type(8))) short bf16x8;
typedef __attribute__((ext_vector_type(4))) float f32x4;
typedef __attribute__((ext_vector_type(2))) float f32x2;
typedef __attribute__((ext_vector_type(4))) unsigned int u32x4;

__device__ __forceinline__ float tanh_fast(float x) {
  float e = __expf(2.0f * x);
  return 1.0f - 2.0f / (e + 1.0f);
}
__device__ __forceinline__ unsigned int f2bf(float f) {
  unsigned int u = __float_as_uint(f);
  return (u + 0x7FFFu + ((u >> 16) & 1u)) >> 16;  // RNE
}
__device__ __forceinline__ unsigned int pack2(float lo, float hi) {
  return f2bf(lo) | (f2bf(hi) << 16);
}

// ---------------- Phase 0: fp32 [K][N] -> bf16 transposed [N][K] -------------
__global__ __launch_bounds__(256) void cvt_transpose(
    const float* __restrict__ src, unsigned short* __restrict__ dst) {
  __shared__ float t[32][33];
  const int bx = blockIdx.x * 32;
  const int by = blockIdx.y * 32;
  const int ty = threadIdx.x >> 3;
  const int tx = threadIdx.x & 7;
  float4 v = *(const float4*)&src[(size_t)(by + ty) * 1024 + bx + tx * 4];
  t[ty][tx * 4 + 0] = v.x; t[ty][tx * 4 + 1] = v.y;
  t[ty][tx * 4 + 2] = v.z; t[ty][tx * 4 + 3] = v.w;
  __syncthreads();
  ushort4 o;
  o.x = (unsigned short)f2bf(t[tx * 4 + 0][ty]);
  o.y = (unsigned short)f2bf(t[tx * 4 + 1][ty]);
  o.z = (unsigned short)f2bf(t[tx * 4 + 2][ty]);
  o.w = (unsigned short)f2bf(t[tx * 4 + 3][ty]);
  *(ushort4*)&dst[(size_t)(bx + ty) * 1024 + by + tx * 4] = o;
}

// ---------------- Phase 1: bf16 MFMA GEMM, 128x128 tile, BK=32 ---------------
__global__ __launch_bounds__(256) void xg_mfma(
    const float* __restrict__ X,            // [M][K] fp32
    const unsigned short* __restrict__ WxT, // [N][K] bf16
    const float* __restrict__ bx, const float* __restrict__ bh,
    float* __restrict__ C) {                // [M][N] fp32
  __shared__ char sAB[16384] __attribute__((aligned(16)));
  char* sA = sAB;
  char* sB = sAB + 8192;
  const int tid = threadIdx.x;
  const int m0 = blockIdx.y * 128;
  const int n0 = blockIdx.x * 128;
  const int w = tid >> 6, l = tid & 63;
  const int wm = (w >> 1) * 64, wn = (w & 1) * 64;
  const int r2 = tid >> 1, kh = tid & 1;

  f32x4 acc[4][4];
#pragma unroll
  for (int i = 0; i < 4; ++i)
#pragma unroll
    for (int j = 0; j < 4; ++j) acc[i][j] = (f32x4){0.f, 0.f, 0.f, 0.f};

  for (int k0 = 0; k0 < Idim; k0 += 32) {
    const float* xa = &X[(size_t)(m0 + r2) * Idim + k0 + kh * 16];
    float4 a0 = *(const float4*)(xa + 0), a1 = *(const float4*)(xa + 4);
    float4 a2 = *(const float4*)(xa + 8), a3 = *(const float4*)(xa + 12);
    const char* wb = (const char*)&WxT[(size_t)(n0 + r2) * Idim + k0 + kh * 16];
    u32x4 b0 = *(const u32x4*)wb;
    u32x4 b1 = *(const u32x4*)(wb + 16);
    __syncthreads();
    u32x4 pa0 = {pack2(a0.x, a0.y), pack2(a0.z, a0.w),
                 pack2(a1.x, a1.y), pack2(a1.z, a1.w)};
    u32x4 pa1 = {pack2(a2.x, a2.y), pack2(a2.z, a2.w),
                 pack2(a3.x, a3.y), pack2(a3.z, a3.w)};
    const int sw = (r2 & 7) << 4;
    const int rb = r2 * 64 + kh * 32;
    *(u32x4*)(sA + ((rb + 0) ^ sw)) = pa0;
    *(u32x4*)(sA + ((rb + 16) ^ sw)) = pa1;
    *(u32x4*)(sB + ((rb + 0) ^ sw)) = b0;
    *(u32x4*)(sB + ((rb + 16) ^ sw)) = b1;
    __syncthreads();
    bf16x8 af[4], bf[4];
#pragma unroll
    for (int i = 0; i < 4; ++i) {
      int ra = wm + i * 16 + (l & 15);
      af[i] = *(const bf16x8*)(sA + ((ra * 64 + (l >> 4) * 16) ^ ((ra & 7) << 4)));
      int rn = wn + i * 16 + (l & 15);
      bf[i] = *(const bf16x8*)(sB + ((rn * 64 + (l >> 4) * 16) ^ ((rn & 7) << 4)));
    }
#pragma unroll
    for (int i = 0; i < 4; ++i)
#pragma unroll
      for (int j = 0; j < 4; ++j)
        acc[i][j] = __builtin_amdgcn_mfma_f32_16x16x32_bf16(af[i], bf[j],
                                                            acc[i][j], 0, 0, 0);
  }
  float bias[4];
#pragma unroll
  for (int j = 0; j < 4; ++j) {
    int cc = n0 + wn + j * 16 + (l & 15);
    bias[j] = bx[cc] + bh[cc];
  }
#pragma unroll
  for (int i = 0; i < 4; ++i) {
    int rbase = m0 + wm + i * 16 + (l >> 4) * 4;
#pragma unroll
    for (int j = 0; j < 4; ++j) {
      int cc = n0 + wn + j * 16 + (l & 15);
#pragma unroll
      for (int r = 0; r < 4; ++r)
        C[(size_t)(rbase + r) * Hdim + cc] = acc[i][j][r] + bias[j];
    }
  }
}

// ---------------- control-region clear (4 KB via MALL) -----------------------
__global__ void clear_flags(unsigned int* flags) {
  __hip_atomic_store(&flags[threadIdx.x], 0u, __ATOMIC_RELAXED,
                     __HIP_MEMORY_SCOPE_AGENT);
}

// ---------------- Phase 2: persistent MFMA scan ------------------------------
// flags layout (dwords): [0..511] fast per-wave flags c*64+m*8+w
//   [512..767] fallback block flags c*32+m   [768..831] xcc map (by bid)
//   [832..839] witness per cluster           [896..959] votes c*8+m
__global__ __launch_bounds__(512, 2) void rnn_scan(
    const unsigned short* __restrict__ WhT,  // [N=1024][K=1024] bf16
    float* __restrict__ out,                 // [B][T][H]: xproj in, h out
    float* __restrict__ hlast,               // [B][H]
    unsigned int* hbuf,                      // ws: [2][64 b][512 cp] dwords
    unsigned int* flags) {
  const int bid = blockIdx.x;
  const int c = bid & 7;   // cluster: batches c*8..+8
  const int m = bid >> 3;  // member: cols m*128..+128
  const int tid = threadIdx.x;
  const int w = tid >> 6;  // wave: k-slice w*128..+128; finisher batch c*8+w
  const int l = tid & 63;
  const int n0 = m * 128;

  __shared__ char smem[16384 + 33792] __attribute__((aligned(16)));
  char* smh = smem;          // h: [8 b][2048 B] bf16, XOR-swizzled
  char* smp = smem + 16384;  // partials: [8 w][8 nt][33][16 B] (lanes 0-31)
  __shared__ int s_fast;

  // ---------- one-time co-location detection ----------
  {
    unsigned int xcc = __builtin_amdgcn_s_getreg(14356) & 0xFFu;  // XCC_ID w8
    if (tid == 0)
      __hip_atomic_store(&flags[768 + bid], 0x100u | xcc, __ATOMIC_RELAXED,
                         __HIP_MEMORY_SCOPE_AGENT);
    if (w == 0) {
      // gather my cluster's 8 xcc values (MALL, throttled)
      const unsigned int* xs = &flags[768 + ((l & 7) << 3) + c];
      unsigned int v;
      for (;;) {
        v = __hip_atomic_load(xs, __ATOMIC_RELAXED, __HIP_MEMORY_SCOPE_AGENT);
        if (__ballot((v & 0x100u) != 0) == ~0ull) break;
        __builtin_amdgcn_s_sleep(8);
      }
      int alleq = (__ballot((v & 0xFFu) == xcc) == ~0ull);
      int myvote = 0;
      if (alleq) {
        unsigned int* wit = &flags[832 + c];
        if (m == 0) {
          if (l == 0) {
            unsigned int magic = 0xC0FFEEu;
            asm volatile("global_store_dword %0, %1, off sc0\n\ts_waitcnt vmcnt(0)"
                         :: "v"(wit), "v"(magic) : "memory");
          }
          myvote = 1;
        } else {
          if (l == 0) {
            for (int it = 0; it < 512 && !myvote; ++it) {
              unsigned int v2;
              asm volatile("global_load_dword %0, %1, off sc0\n\ts_waitcnt vmcnt(0)"
                           : "=v"(v2) : "v"(wit) : "memory");
              if (v2 == 0xC0FFEEu) myvote = 1;
            }
          }
          myvote = __shfl(myvote, 0);
        }
        if (l == 0)
          __hip_atomic_store(&flags[896 + c * 8 + m], 0x100u | (unsigned)myvote,
                             __ATOMIC_RELAXED, __HIP_MEMORY_SCOPE_AGENT);
        const unsigned int* vs = &flags[896 + c * 8 + (l & 7)];
        unsigned int vv;
        for (;;) {
          vv = __hip_atomic_load(vs, __ATOMIC_RELAXED, __HIP_MEMORY_SCOPE_AGENT);
          if (__ballot((vv & 0x100u) != 0) == ~0ull) break;
          __builtin_amdgcn_s_sleep(8);
        }
        if (l == 0) s_fast = (__ballot((vv & 1u) != 0) == ~0ull) ? 1 : 0;
      } else {
        if (l == 0) s_fast = 0;
      }
    }
  }
  __syncthreads();
  const bool fast = (s_fast != 0);

  // B-frags: Wh[k=w*128..+128][cols n0..+128] -> 8 nt x 4 kt = 128 regs/lane
  bf16x8 bfrag[32];
  {
    const int kb = (w << 7) + ((l >> 4) << 3);
    const int col = n0 + (l & 15);
#pragma unroll
    for (int nt = 0; nt < 8; ++nt)
#pragma unroll
      for (int kt = 0; kt < 4; ++kt)
        bfrag[nt * 4 + kt] =
            *(const bf16x8*)&WhT[(size_t)(col + nt * 16) * 1024 + kb + kt * 32];
  }

  // finisher: (batch fb = w, col pair c0 = 2*l)
  const int c0 = l * 2;
  const int b_abs = c * 8 + w;
  const int nt0 = c0 >> 4;
  const int lane0 = ((w >> 2) << 4) | (c0 & 15);  // 0..31
  const int regb = (w & 3) * 4;
  const size_t obase = (size_t)b_abs * ((size_t)Tdim * Hdim) + n0 + c0;
  unsigned int* fflag = &flags[c * 64 + m * 8 + w];
  const unsigned int* fpoll = &flags[c * 64 + l];
  unsigned int* bflag = &flags[512 + c * 32 + m];
  const unsigned int* bpoll = &flags[512 + c * 32 + (l & 7)];
  unsigned int* pub = &hbuf[(size_t)b_abs * 512 + m * 64 + l];

  float2 xp = *(const float2*)&out[obase];  // xproj t=0

  for (int t = 0; t < Tdim; ++t) {
    float sum0 = 0.f, sum1 = 0.f;
    if (t > 0) {
      const int arow = l & 7;
      const int abase = arow * 2048 + (w << 8) + ((l >> 4) << 4);
      const int sw = arow << 4;
      bf16x8 af[4];
#pragma unroll
      for (int kt = 0; kt < 4; ++kt)
        af[kt] = *(const bf16x8*)(smh + ((abase + kt * 64) ^ sw));
#pragma unroll
      for (int nt = 0; nt < 8; ++nt) {
        f32x4 a = {0.f, 0.f, 0.f, 0.f};
#pragma unroll
        for (int kt = 0; kt < 4; ++kt)
          a = __builtin_amdgcn_mfma_f32_16x16x32_bf16(af[kt], bfrag[nt * 4 + kt],
                                                      a, 0, 0, 0);
        if (l < 32)  // lanes 32-63 hold duplicate rows: discard
          *(f32x4*)(smp + (((w * 8 + nt) * 33 + l) << 4)) = a;
      }
      asm volatile("s_waitcnt lgkmcnt(0)" ::: "memory");
      __builtin_amdgcn_s_barrier();  // #A: partials visible
      asm volatile("" ::: "memory");
#pragma unroll
      for (int w8 = 0; w8 < 8; ++w8) {
        const char* p = smp + (((w8 * 8 + nt0) * 33 + lane0) << 4) + regb;
        sum0 += *(const float*)p;
        sum1 += *(const float*)(p + 16);
      }
    }
    float h0 = tanh_fast(xp.x + sum0);
    float h1 = tanh_fast(xp.y + sum1);
    if (t == Tdim - 1) {
      *(float2*)&out[obase + (size_t)t * Hdim] = make_float2(h0, h1);
      *(float2*)&hlast[(size_t)b_abs * Hdim + n0 + c0] = make_float2(h0, h1);
      break;
    }
    const int par = (t + 1) & 1;
    const unsigned int tp1 = (unsigned int)(t + 1);
    unsigned int pv = pack2(h0, h1);
    if (fast) {
      // ---------- FAST: all sync through the XCD's own L2 (sc0 only) -------
      char* pubp = (char*)(pub + par * 32768);
      asm volatile("global_store_dword %0, %1, off sc0\n\ts_waitcnt vmcnt(0)"
                   :: "v"(pubp), "v"(pv) : "memory");
      if (l == 0)
        asm volatile("global_store_dword %0, %1, off sc0"
                     :: "v"(fflag), "v"(tp1) : "memory");
      for (;;) {
        unsigned int v;
        asm volatile("global_load_dword %0, %1, off sc0\n\ts_waitcnt vmcnt(0)"
                     : "=v"(v) : "v"(fpoll) : "memory");
        if (__ballot(v >= tp1) == ~0ull) break;
      }
      const char* srcp = (const char*)hbuf + (size_t)par * 131072 +
                         (size_t)b_abs * 2048 + l * 32;
      const float* xpp = &out[obase + (size_t)(t + 1) * Hdim];
      float* outp = &out[obase + (size_t)t * Hdim];
      f32x2 hp; hp[0] = h0; hp[1] = h1;
      u32x4 d0, d1; f32x2 xpd;
      asm volatile(
          "global_load_dwordx4 %0, %3, off sc0\n\t"
          "global_load_dwordx4 %1, %3, off offset:16 sc0\n\t"
          "global_load_dwordx2 %2, %4, off\n\t"
          "global_store_dwordx2 %5, %6, off nt\n\t"
          "s_waitcnt vmcnt(1)"  // waits the 3 loads; out-store keeps flying
          : "=&v"(d0), "=&v"(d1), "=&v"(xpd)
          : "v"(srcp), "v"(xpp), "v"(outp), "v"(hp)
          : "memory");
      __builtin_amdgcn_sched_barrier(0);
      xp.x = xpd[0]; xp.y = xpd[1];
      const int base = w * 2048 + l * 32;
      const int sw2 = w << 4;
      *(u32x4*)(smh + (base ^ sw2)) = d0;
      *(u32x4*)(smh + ((base + 16) ^ sw2)) = d1;
    } else {
      // ---------- FALLBACK: R7-proven MALL protocol ------------------------
      __hip_atomic_store(pub + par * 32768, pv, __ATOMIC_RELAXED,
                         __HIP_MEMORY_SCOPE_AGENT);
      asm volatile("" ::: "memory");
      *(float2*)&out[obase + (size_t)t * Hdim] = make_float2(h0, h1);
      xp = *(const float2*)&out[obase + (size_t)(t + 1) * Hdim];
      asm volatile("s_waitcnt vmcnt(2)" ::: "memory");
      __builtin_amdgcn_s_barrier();  // #B: publishes acked
      asm volatile("" ::: "memory");
      if (tid == 0)
        __hip_atomic_store(bflag, tp1, __ATOMIC_RELAXED,
                           __HIP_MEMORY_SCOPE_AGENT);
      if (w == 7) {
        for (;;) {
          unsigned int v;
          asm volatile(
              "global_load_dword %0, %1, off sc0 sc1\n\ts_waitcnt vmcnt(0)"
              : "=v"(v) : "v"(bpoll) : "memory");
          if (__ballot(v >= tp1) == ~0ull) break;
          __builtin_amdgcn_s_sleep(2);
        }
      }
      asm volatile("" ::: "memory");
      __builtin_amdgcn_s_barrier();  // #C: flags observed
      asm volatile("" ::: "memory");
      const char* srcp = (const char*)hbuf + (size_t)par * 131072 +
                         (size_t)b_abs * 2048 + l * 32;
      u32x4 d0, d1;
      asm volatile(
          "global_load_dwordx4 %0, %2, off sc0 sc1\n\t"
          "global_load_dwordx4 %1, %2, off offset:16 sc0 sc1\n\t"
          "s_waitcnt vmcnt(0)"
          : "=&v"(d0), "=&v"(d1) : "v"(srcp) : "memory");
      __builtin_amdgcn_sched_barrier(0);
      const int base = w * 2048 + l * 32;
      const int sw2 = w << 4;
      *(u32x4*)(smh + (base ^ sw2)) = d0;
      *(u32x4*)(smh + ((base + 16) ^ sw2)) = d1;
    }
    asm volatile("s_waitcnt lgkmcnt(0)" ::: "memory");
    __builtin_amdgcn_s_barrier();  // #D: h_{t+1} staged
    asm volatile("" ::: "memory");
  }
}

extern "C" void kernel_launch(void* const* d_in, const int* in_sizes, int n_in,
                              void* d_out, int out_size, void* d_ws,
                              size_t ws_size, hipStream_t stream) {
  const float* x  = (const float*)d_in[0];
  const float* Wx = (const float*)d_in[1];
  const float* bx = (const float*)d_in[2];
  const float* Wh = (const float*)d_in[3];
  const float* bh = (const float*)d_in[4];
  float* out = (float*)d_out;
  float* hlast = out + (size_t)Bdim * Tdim * Hdim;
  unsigned int* flags = (unsigned int*)d_ws;                       // 4 KB
  unsigned int* hbuf = (unsigned int*)((char*)d_ws + 4096);        // 256 KB
  unsigned short* WxT = (unsigned short*)((char*)d_ws + 4096 + 262144);
  unsigned short* WhT = (unsigned short*)((char*)d_ws + 4096 + 262144 + 2097152);

  clear_flags<<<1, dim3(1024), 0, stream>>>(flags);
  dim3 gt(32, 32);
  cvt_transpose<<<gt, dim3(256), 0, stream>>>(Wx, WxT);
  cvt_transpose<<<gt, dim3(256), 0, stream>>>(Wh, WhT);
  xg_mfma<<<dim3(Hdim / 128, Mdim / 128), dim3(256), 0, stream>>>(x, WxT, bx,
                                                                  bh, out);
  rnn_scan<<<dim3(64), dim3(512), 0, stream>>>(WhT, out, hlast, hbuf, flags);
}